// Round 1
// baseline (915.035 us; speedup 1.0000x reference)
//
#include <hip/hip_runtime.h>

// ---------------------------------------------------------------------------
// DAG-masked single-head attention, B=64 T=1024 D=H=512, f32 in/out.
// Pipeline: cvt(X,Y)->bf16 ; Wt transposes ; dagT transpose ;
//   K = Xb@Wkt^T + bk            [65536x512]
//   Q = (Yb@Wqt^T + bq)/sqrt(H)  [65536x512]  (scale folded)
//   Vt[b][h][t] = Wvt@Xb_b^T + bv (batched, writes V pre-transposed)
//   attn: per block (128 q-rows, one batch): flash loop over 16 KV-tiles of 64,
//         no-max softmax (S bounded), P via LDS, Vt b-frags from L2.
// ---------------------------------------------------------------------------

typedef __attribute__((ext_vector_type(8))) short s8v;      // 8 x bf16
typedef __attribute__((ext_vector_type(4))) float f4v;
typedef __attribute__((ext_vector_type(4))) unsigned short us4;

#define MFMA16(a, b, c) __builtin_amdgcn_mfma_f32_16x16x32_bf16(a, b, c, 0, 0, 0)
#define GLOAD_LDS16(gp, lp)                                                    \
  __builtin_amdgcn_global_load_lds(                                            \
      (const __attribute__((address_space(1))) unsigned*)(gp),                 \
      (__attribute__((address_space(3))) unsigned*)(lp), 16, 0, 0)

__device__ __forceinline__ unsigned short f2b(float f) {
  union { float f; unsigned u; } v; v.f = f;
  return (unsigned short)((v.u + 0x7fffu + ((v.u >> 16) & 1u)) >> 16);
}
__device__ __forceinline__ float b2f(unsigned short h) {
  union { unsigned u; float f; } v; v.u = ((unsigned)h) << 16;
  return v.f;
}

// ---------------- convert f32 -> bf16, vectorized ----------------
__global__ void cvt_bf16(const float* __restrict__ in,
                         unsigned short* __restrict__ out, size_t n) {
  size_t i = ((size_t)blockIdx.x * blockDim.x + threadIdx.x) * 4;
  size_t stride = (size_t)gridDim.x * blockDim.x * 4;
  for (; i < n; i += stride) {
    f4v v = *(const f4v*)(in + i);
    us4 r;
    r.x = f2b(v.x); r.y = f2b(v.y); r.z = f2b(v.z); r.w = f2b(v.w);
    *(us4*)(out + i) = r;
  }
}

// ---------------- transpose + convert: out[j][i] = bf16(in[i][j]) ----------
__global__ void transpose_cvt(const float* __restrict__ in,
                              unsigned short* __restrict__ out, int n) {
  __shared__ float t[32][33];
  const int bx = blockIdx.x * 32, by = blockIdx.y * 32;
  const int x = threadIdx.x, y = threadIdx.y;  // 32 x 8
#pragma unroll
  for (int dy = 0; dy < 32; dy += 8)
    t[y + dy][x] = in[(size_t)(by + y + dy) * n + bx + x];
  __syncthreads();
#pragma unroll
  for (int dy = 0; dy < 32; dy += 8)
    out[(size_t)(bx + y + dy) * n + by + x] = f2b(t[x][y + dy]);
}

// ---------------- NT GEMM: C[M][N] = bf16((A @ B^T + bias) * scale) --------
// A[M][Kd], B[N][Kd] row-major bf16. biasMode 0: bias[n]; 1: bias[m].
// BM=BN=128, BK=64, 4 waves (2x2), wave tile 64x64.
__global__ __launch_bounds__(256, 2)
void gemm_nt(const unsigned short* __restrict__ A,
             const unsigned short* __restrict__ Bm,
             unsigned short* __restrict__ C, const float* __restrict__ bias,
             int M, int N, int Kd, int biasMode, float scale,
             long strideA, long strideB, long strideC) {
  A += (size_t)blockIdx.z * strideA;
  Bm += (size_t)blockIdx.z * strideB;
  C += (size_t)blockIdx.z * strideC;
  const int m0 = blockIdx.y * 128, n0 = blockIdx.x * 128;
  __shared__ unsigned short Asm[2][128 * 64];
  __shared__ unsigned short Bsm[2][128 * 64];
  const int tid = threadIdx.x;
  const int lane = tid & 63, wid = tid >> 6;
  const int wm = wid >> 1, wn = wid & 1;
  const int g = lane >> 4, lr = lane & 15;
  const size_t ldb = (size_t)Kd * 2;  // row bytes

  f4v acc[4][4] = {};
  const char* Ab = (const char*)A;
  const char* Bb = (const char*)Bm;

  // prologue: stage kt=0 into buf 0 (linear LDS dest, inverse-swizzled source)
#pragma unroll
  for (int i = 0; i < 4; ++i) {
    int sb = (wid * 4 + i) * 64;
    int p = (sb + lane) * 16;
    int row = p >> 7, colb = p & 127;
    int sc = colb ^ ((row & 7) << 4);
    GLOAD_LDS16(Ab + (size_t)(m0 + row) * ldb + sc, ((char*)Asm[0]) + sb * 16);
    GLOAD_LDS16(Bb + (size_t)(n0 + row) * ldb + sc, ((char*)Bsm[0]) + sb * 16);
  }
  const int nk = Kd >> 6;
  int buf = 0;
  for (int kt = 0; kt < nk; ++kt) {
    __syncthreads();
    if (kt + 1 < nk) {
      const int kb = (kt + 1) << 7;
#pragma unroll
      for (int i = 0; i < 4; ++i) {
        int sb = (wid * 4 + i) * 64;
        int p = (sb + lane) * 16;
        int row = p >> 7, colb = p & 127;
        int sc = colb ^ ((row & 7) << 4);
        GLOAD_LDS16(Ab + (size_t)(m0 + row) * ldb + kb + sc,
                    ((char*)Asm[buf ^ 1]) + sb * 16);
        GLOAD_LDS16(Bb + (size_t)(n0 + row) * ldb + kb + sc,
                    ((char*)Bsm[buf ^ 1]) + sb * 16);
      }
    }
    const char* As = (const char*)Asm[buf];
    const char* Bs = (const char*)Bsm[buf];
#pragma unroll
    for (int ks = 0; ks < 2; ++ks) {
      s8v af[4], bfr[4];
#pragma unroll
      for (int mi = 0; mi < 4; ++mi) {
        int row = wm * 64 + mi * 16 + lr;
        int cb = (ks * 32 + g * 8) * 2;
        af[mi] = *(const s8v*)(As + row * 128 + (cb ^ ((row & 7) << 4)));
      }
#pragma unroll
      for (int ni = 0; ni < 4; ++ni) {
        int row = wn * 64 + ni * 16 + lr;
        int cb = (ks * 32 + g * 8) * 2;
        bfr[ni] = *(const s8v*)(Bs + row * 128 + (cb ^ ((row & 7) << 4)));
      }
#pragma unroll
      for (int mi = 0; mi < 4; ++mi)
#pragma unroll
        for (int ni = 0; ni < 4; ++ni)
          acc[mi][ni] = MFMA16(af[mi], bfr[ni], acc[mi][ni]);
    }
    buf ^= 1;
  }
  // epilogue
  if (biasMode == 0) {
    float bvv[4];
#pragma unroll
    for (int ni = 0; ni < 4; ++ni) bvv[ni] = bias[n0 + wn * 64 + ni * 16 + lr];
#pragma unroll
    for (int mi = 0; mi < 4; ++mi)
#pragma unroll
      for (int r = 0; r < 4; ++r) {
        int row = m0 + wm * 64 + mi * 16 + g * 4 + r;
        size_t rb = (size_t)row * N;
#pragma unroll
        for (int ni = 0; ni < 4; ++ni)
          C[rb + n0 + wn * 64 + ni * 16 + lr] =
              f2b((acc[mi][ni][r] + bvv[ni]) * scale);
      }
  } else {
#pragma unroll
    for (int mi = 0; mi < 4; ++mi)
#pragma unroll
      for (int r = 0; r < 4; ++r) {
        int row = m0 + wm * 64 + mi * 16 + g * 4 + r;
        float bvr = bias[row];
        size_t rb = (size_t)row * N;
#pragma unroll
        for (int ni = 0; ni < 4; ++ni)
          C[rb + n0 + wn * 64 + ni * 16 + lr] = f2b(acc[mi][ni][r] + bvr);
      }
  }
}

// ---------------- fused DAG-masked attention ----------------
// grid (8 qtiles, 64 batches), 512 threads (8 waves).
// QK^T: wave w owns q-rows 16w..16w+15 (Q persistent in regs), K staged LDS.
// softmax: no-max (S bounded ~|30|): p = (dagT*S==0) ? 0 : exp(S); l-sum f32.
// PV: wave w owns h-chunk 64w..64w+63 for all 128 t; P via LDS; Vt from L2.
__global__ __launch_bounds__(512, 2)
void attn_kernel(const unsigned short* __restrict__ Qb,
                 const unsigned short* __restrict__ Kb,
                 const unsigned short* __restrict__ Vt,
                 const unsigned short* __restrict__ dagT,
                 float* __restrict__ Out) {
  __shared__ unsigned short Ksm[64 * 512];   // 64 KB, XOR-swizzled rows
  __shared__ unsigned short Psm[128 * 64];   // 16 KB, XOR-swizzled rows
  __shared__ float Lsm[128];
  const int b = blockIdx.y;
  const int t0 = blockIdx.x * 128;
  const int tid = threadIdx.x, lane = tid & 63, w = tid >> 6;
  const int g = lane >> 4, lr = lane & 15;
  const size_t bTH = (size_t)b * 524288;  // b*1024*512

  // persistent Q a-frags: Q[t0+16w+lr][kk*32 + g*8 .. +7]
  s8v qf[16];
  {
    const char* Qp = (const char*)Qb + (bTH + (size_t)(t0 + 16 * w + lr) * 512) * 2;
#pragma unroll
    for (int kk = 0; kk < 16; ++kk)
      qf[kk] = *(const s8v*)(Qp + (kk * 32 + g * 8) * 2);
  }
  f4v oacc[8][4] = {};
  float lpart[4] = {0.f, 0.f, 0.f, 0.f};
  const char* Kbase = (const char*)(Kb + bTH);
  const unsigned short* Vtb = Vt + bTH;  // Vt[b][h][t]

  for (int st = 0; st < 16; ++st) {
    const int s0 = st * 64;
    // stage K tile [64][512] bf16 (4096 16B slots, 8 issues/wave)
    {
      const char* Kp = Kbase + (size_t)s0 * 1024;
#pragma unroll
      for (int i = 0; i < 8; ++i) {
        int sb = (w * 8 + i) * 64;
        int p = (sb + lane) * 16;
        int row = p >> 10, colb = p & 1023;
        int sc = colb ^ ((row & 7) << 4);
        GLOAD_LDS16(Kp + row * 1024 + sc, ((char*)Ksm) + sb * 16);
      }
    }
    __syncthreads();
    // QK^T: S[16t x 64s] per wave
    f4v sa[4] = {};
#pragma unroll
    for (int kk = 0; kk < 16; ++kk) {
#pragma unroll
      for (int j = 0; j < 4; ++j) {
        int row = j * 16 + lr;
        int cb = (kk * 32 + g * 8) * 2;
        s8v bf = *(const s8v*)(((const char*)Ksm) + row * 1024 +
                               (cb ^ ((row & 7) << 4)));
        sa[j] = MFMA16(qf[kk], bf, sa[j]);
      }
    }
    // mask + exp + write P (C/D layout: s-col = lr(+16j), t-row = 4g+r)
#pragma unroll
    for (int j = 0; j < 4; ++j) {
      int sidx = s0 + j * 16 + lr;
#pragma unroll
      for (int r = 0; r < 4; ++r) {
        int tloc = 16 * w + 4 * g + r;
        float mval = b2f(dagT[(size_t)(t0 + tloc) * 1024 + sidx]);
        float sp = mval * sa[j][r];
        float p = (sp == 0.0f) ? 0.0f : __expf(sp);  // matches Sp==0 -> -1e30
        lpart[r] += p;
        int pc = (j * 16 + lr) * 2;
        *(unsigned short*)(((char*)Psm) + tloc * 128 +
                           (pc ^ ((tloc & 7) << 4))) = f2b(p);
      }
    }
    __syncthreads();
    // PV: O[128t x 64h-chunk] += P @ Vt^T (NT: B-rows = Vt[h][s])
#pragma unroll
    for (int ks = 0; ks < 2; ++ks) {
      s8v vf[4];
#pragma unroll
      for (int ni = 0; ni < 4; ++ni)
        vf[ni] = *(const s8v*)((const char*)(Vtb +
                     (size_t)(64 * w + 16 * ni + lr) * 1024) +
                     (s0 + ks * 32 + g * 8) * 2);
#pragma unroll
      for (int mi = 0; mi < 8; ++mi) {
        int pr = mi * 16 + lr;
        int pc = (ks * 32 + g * 8) * 2;
        s8v af = *(const s8v*)(((const char*)Psm) + pr * 128 +
                               (pc ^ ((pr & 7) << 4)));
#pragma unroll
        for (int ni = 0; ni < 4; ++ni)
          oacc[mi][ni] = MFMA16(af, vf[ni], oacc[mi][ni]);
      }
    }
  }
  // epilogue: reduce l across the 16-lane groups, then O /= l (dead row -> 0)
#pragma unroll
  for (int r = 0; r < 4; ++r) {
    float v = lpart[r];
    v += __shfl_xor(v, 1);
    v += __shfl_xor(v, 2);
    v += __shfl_xor(v, 4);
    v += __shfl_xor(v, 8);
    if (lr == 0) Lsm[16 * w + 4 * g + r] = v;
  }
  __syncthreads();
  float* Ob = Out + ((size_t)b * 1024 + t0) * 512;
#pragma unroll
  for (int mi = 0; mi < 8; ++mi)
#pragma unroll
    for (int r = 0; r < 4; ++r) {
      int tloc = mi * 16 + 4 * g + r;
      float l = Lsm[tloc];
      float inv = (l > 0.0f) ? 1.0f / l : 0.0f;
      float* rowp = Ob + (size_t)tloc * 512 + 64 * w + lr;
#pragma unroll
      for (int ni = 0; ni < 4; ++ni) rowp[ni * 16] = oacc[mi][ni][r] * inv;
    }
}

// ---------------------------------------------------------------------------
extern "C" void kernel_launch(void* const* d_in, const int* in_sizes, int n_in,
                              void* d_out, int out_size, void* d_ws,
                              size_t ws_size, hipStream_t stream) {
  const float* X   = (const float*)d_in[0];
  const float* Y   = (const float*)d_in[1];
  const float* dag = (const float*)d_in[2];
  const float* Wk  = (const float*)d_in[3];
  const float* bk  = (const float*)d_in[4];
  const float* Wq  = (const float*)d_in[5];
  const float* bq  = (const float*)d_in[6];
  const float* Wv  = (const float*)d_in[7];
  const float* bv  = (const float*)d_in[8];
  float* Out = (float*)d_out;

  char* ws = (char*)d_ws;
  // ws layout (bytes): 5 x 64MB bf16 tensors + 3 x 512KB Wt + 2MB dagT = ~324MB
  unsigned short* Xb   = (unsigned short*)(ws);
  unsigned short* Yb   = (unsigned short*)(ws + 67108864);
  unsigned short* Kb   = (unsigned short*)(ws + 134217728);
  unsigned short* Qb   = (unsigned short*)(ws + 201326592);
  unsigned short* Vt   = (unsigned short*)(ws + 268435456);
  unsigned short* Wkt  = (unsigned short*)(ws + 335544320);
  unsigned short* Wqt  = (unsigned short*)(ws + 336068608);
  unsigned short* Wvt  = (unsigned short*)(ws + 336592896);
  unsigned short* dagT = (unsigned short*)(ws + 337117184);

  const size_t EL = 33554432;  // 64*1024*512
  cvt_bf16<<<dim3(2048), dim3(256), 0, stream>>>(X, Xb, EL);
  cvt_bf16<<<dim3(2048), dim3(256), 0, stream>>>(Y, Yb, EL);
  transpose_cvt<<<dim3(16, 16), dim3(32, 8), 0, stream>>>(Wk, Wkt, 512);
  transpose_cvt<<<dim3(16, 16), dim3(32, 8), 0, stream>>>(Wq, Wqt, 512);
  transpose_cvt<<<dim3(16, 16), dim3(32, 8), 0, stream>>>(Wv, Wvt, 512);
  transpose_cvt<<<dim3(32, 32), dim3(32, 8), 0, stream>>>(dag, dagT, 1024);

  // K = Xb @ Wkt^T + bk
  gemm_nt<<<dim3(4, 512, 1), dim3(256), 0, stream>>>(
      Xb, Wkt, Kb, bk, 65536, 512, 512, 0, 1.0f, 0, 0, 0);
  // Q = (Yb @ Wqt^T + bq) / sqrt(512)
  gemm_nt<<<dim3(4, 512, 1), dim3(256), 0, stream>>>(
      Yb, Wqt, Qb, bq, 65536, 512, 512, 0, 0.04419417382415922f, 0, 0, 0);
  // Vt[b] = Wvt @ Xb_b^T + bv  (M=512 h, N=1024 t, batched over z)
  gemm_nt<<<dim3(8, 4, 64), dim3(256), 0, stream>>>(
      Wvt, Xb, Vt, bv, 512, 1024, 512, 1, 1.0f, 0, (long)524288, (long)524288);

  attn_kernel<<<dim3(8, 64, 1), dim3(512), 0, stream>>>(Qb, Kb, Vt, dagT, Out);
}